// Round 3
// baseline (77.501 us; speedup 1.0000x reference)
//
#include <hip/hip_runtime.h>
#include <math.h>

// TropConv2D: out[b,ho,wo,f] = max_k(patch + w) - min_k(patch + w) + bias
// B=8, H=W=32, C=32, KH=KW=3, F=64, Ho=Wo=30, K=288. 7200 output pixels.
//
// R5 structure: 512-thread blocks (8 waves), wave owns PIX=2 pixels,
// lane = filter.
//  * w staged into LDS TRANSPOSED + padded: wT[f][k], stride 292
//    (288+4 pad; 73 = stride/4 is odd -> coprime with 32 banks ->
//    ds_read_b128 start banks are a permutation across lanes, optimal
//    8 accesses/bank). Inner loop reads w as ONE ds_read_b128 per
//    4 k-values instead of 4 lane-strided ds_read_b32: 72 DS ops/wave
//    instead of 288, at the efficient b128 width (85 B/cyc vs 44).
//  * x loads stay VMEM (no readfirstlane!): mixing s_load with ds_read
//    in lgkmcnt forces conservative lgkmcnt(0) drains (SMEM and DS
//    retire out-of-order w.r.t. each other). With x in vmcnt and LDS
//    pure-DS, the compiler emits fine-grained lgkmcnt(N) waits.
//  * One barrier per block (R4), max3/min3 reassociation (R3).
//  * __launch_bounds__(512,4): cap VGPR at 128 so the LDS-allowed
//    2 blocks/CU = 4 waves/SIMD is actually reachable.

#define TPB 512  // 8 waves
#define PIX 2
#define WSTRIDE 292  // 288 + 4 pad floats; 292*4 B row pitch, 16B aligned

__device__ __forceinline__ float fmax3(float a, float b, float c) {
    return fmaxf(fmaxf(a, b), c);
}
__device__ __forceinline__ float fmin3(float a, float b, float c) {
    return fminf(fminf(a, b), c);
}

__global__ __launch_bounds__(TPB, 4) void trop_kernel(
    const float* __restrict__ x,     // (8,32,32,32)
    const float* __restrict__ w,     // (288,64) = 9 taps * (32,64)
    const float* __restrict__ bias,  // (64,)
    float* __restrict__ out)         // (8,30,30,64) = (7200,64)
{
    extern __shared__ float wlds[];  // 64 * 292 floats = 74752 B (wT, padded)

    const int tid  = threadIdx.x;
    const int lane = tid & 63;
    const int wv   = tid >> 6;

    const int pix0 = blockIdx.x * (8 * PIX) + wv * PIX;  // 0..7198

    // Stage + transpose w: 4608 float4 coalesced reads, scatter to wT[f][k].
    // Write banks: lane l, component j -> bank ~ (4m + 73j) mod 32, 2-way
    // aliasing per bank across the wave = free.
    {
        const float4* src = (const float4*)w;
#pragma unroll
        for (int i = 0; i < 9; ++i) {
            const int e4 = tid + i * 512;      // float4 index, < 4608
            const float4 v = src[e4];
            const int k = e4 >> 4;             // = (4*e4)/64
            const int f = (e4 & 15) * 4;       // = (4*e4)%64
            wlds[(f + 0) * WSTRIDE + k] = v.x;
            wlds[(f + 1) * WSTRIDE + k] = v.y;
            wlds[(f + 2) * WSTRIDE + k] = v.z;
            wlds[(f + 3) * WSTRIDE + k] = v.w;
        }
    }

    // Per-pixel x base pointers (per-wave values; stay VMEM).
    const float* xp[PIX];
#pragma unroll
    for (int p = 0; p < PIX; ++p) {
        const int pid = pix0 + p;
        const int wo = pid % 30;
        const int t  = pid / 30;
        const int ho = t % 30;
        const int b  = t / 30;
        xp[p] = x + (((b * 32 + ho) * 32) + wo) * 32;
    }

    float amax[PIX], amin[PIX];
#pragma unroll
    for (int p = 0; p < PIX; ++p) { amax[p] = -INFINITY; amin[p] = INFINITY; }

    __syncthreads();  // the only barrier

    const float* wrow = wlds + lane * WSTRIDE;  // this lane's filter row

#pragma unroll
    for (int tap = 0; tap < 9; ++tap) {
        const int dy = tap / 3;
        const int dx = tap % 3;
        const int xoff = (dy * 32 + dx) * 32;
#pragma unroll
        for (int c = 0; c < 32; c += 4) {
            // One b128 per 4 k-values: base VGPR = lane*WSTRIDE, offset imm.
            const float4 wv4 = *(const float4*)(wrow + tap * 32 + c);
#pragma unroll
            for (int p = 0; p < PIX; ++p) {
                const float4 xv = *(const float4*)(xp[p] + xoff + c);  // wave-uniform VMEM
                const float s0 = xv.x + wv4.x;
                const float s1 = xv.y + wv4.y;
                const float s2 = xv.z + wv4.z;
                const float s3 = xv.w + wv4.w;
                amax[p] = fmax3(amax[p], fmax3(s0, s1, s2), s3);
                amin[p] = fmin3(amin[p], fmin3(s0, s1, s2), s3);
            }
        }
    }

    const float bv = bias[lane];
#pragma unroll
    for (int p = 0; p < PIX; ++p)
        out[(pix0 + p) * 64 + lane] = amax[p] - amin[p] + bv;
}

extern "C" void kernel_launch(void* const* d_in, const int* in_sizes, int n_in,
                              void* d_out, int out_size, void* d_ws, size_t ws_size,
                              hipStream_t stream) {
    const float* x    = (const float*)d_in[0];
    const float* w    = (const float*)d_in[1];
    const float* bias = (const float*)d_in[2];
    float* out = (float*)d_out;

    // 74752 B dynamic LDS (64*292 floats); 2 blocks/CU on 160 KiB.
    static int attr_done = 0;
    if (!attr_done) {
        (void)hipFuncSetAttribute((const void*)trop_kernel,
                                  hipFuncAttributeMaxDynamicSharedMemorySize,
                                  74752);
        attr_done = 1;
    }

    // 7200 pixels / (8 waves * 2 pixels) = 450 blocks
    trop_kernel<<<dim3(450), dim3(TPB), 74752, stream>>>(x, w, bias, out);
}

// Round 4
// 73.782 us; speedup vs baseline: 1.0504x; 1.0504x over previous
//
#include <hip/hip_runtime.h>
#include <math.h>

// TropConv2D: out[b,ho,wo,f] = max_k(patch + w) - min_k(patch + w) + bias
// B=8, H=W=32, C=32, KH=KW=3, F=64, Ho=Wo=30, K=288. 7200 output pixels.
//
// R6 = R4 (best: kernel ~27.6us) with ONE change: PIX 2->4, TPB 512->256.
// R4 model: LDS-pipe-bound -- 288 ds_read_b32 per wave amortized over PIX
// pixels; per-CU LDS cost scales 1/PIX (9.8us @ PIX=2 -> 4.9us @ PIX=4).
// Kept from R4 (do NOT re-break):
//  * w[k][f] LINEAR in LDS; staging = coalesced float4, conflict-free.
//    (R5's transposed staging had 8-way write conflicts: bank
//    (16m+k)%32 hits 2 banks/16 lanes -- that was the regression.)
//  * x via readfirstlane -> s_load (SMEM): removes VMEM latency chain
//    from the inner loop; R4 (s_load) beat R0/R5 (VMEM) by ~9us.
//  * ONE barrier per block; max3/min3 reassociation.
// 450 blocks, 72KiB LDS -> 2 blocks/CU, 8 waves/CU, 4 independent
// pixel chains per wave for ILP.

#define TPB 256  // 4 waves
#define PIX 4

__device__ __forceinline__ float fmax3(float a, float b, float c) {
    return fmaxf(fmaxf(a, b), c);
}
__device__ __forceinline__ float fmin3(float a, float b, float c) {
    return fminf(fminf(a, b), c);
}

__global__ __launch_bounds__(TPB) void trop_kernel(
    const float* __restrict__ x,     // (8,32,32,32)
    const float* __restrict__ w,     // (288,64) = 9 taps * (32,64)
    const float* __restrict__ bias,  // (64,)
    float* __restrict__ out)         // (8,30,30,64) = (7200,64)
{
    extern __shared__ float wlds[];  // 18432 floats = 72 KiB, w[k][f] linear

    const int tid  = threadIdx.x;
    const int lane = tid & 63;
    const int wv   = tid >> 6;

    const int pix0 = blockIdx.x * (4 * PIX) + wv * PIX;  // 0..7196

    // Stage ALL of w: 4608 float4 across 256 threads = 18 each.
    // Coalesced global float4; LDS writes lane-consecutive -> conflict-free.
    {
        const float4* src = (const float4*)w;
        float4* dst = (float4*)wlds;
#pragma unroll
        for (int i = 0; i < 18; ++i) dst[tid + i * 256] = src[tid + i * 256];
    }

    // Wave-uniform x base offsets (floats), proven uniform via
    // readfirstlane so x reads become s_load (SMEM pipe, no VMEM chain).
    int xoffp[PIX];
#pragma unroll
    for (int p = 0; p < PIX; ++p) {
        const int pid = pix0 + p;
        const int wo = pid % 30;
        const int t  = pid / 30;
        const int ho = t % 30;
        const int b  = t / 30;
        xoffp[p] = __builtin_amdgcn_readfirstlane((((b * 32 + ho) * 32) + wo) * 32);
    }

    float amax[PIX], amin[PIX];
#pragma unroll
    for (int p = 0; p < PIX; ++p) { amax[p] = -INFINITY; amin[p] = INFINITY; }

    __syncthreads();  // the only barrier

#pragma unroll
    for (int tap = 0; tap < 9; ++tap) {
        const int dy = tap / 3;
        const int dx = tap % 3;
        const int xoff = (dy * 32 + dx) * 32;
        const float* wl = wlds + tap * 2048;
#pragma unroll
        for (int c = 0; c < 32; c += 4) {
            const float w0 = wl[(c + 0) * 64 + lane];
            const float w1 = wl[(c + 1) * 64 + lane];
            const float w2 = wl[(c + 2) * 64 + lane];
            const float w3 = wl[(c + 3) * 64 + lane];
#pragma unroll
            for (int p = 0; p < PIX; ++p) {
                const float* xb = x + xoffp[p] + xoff;  // scalar (SGPR) address
                const float s0 = xb[c + 0] + w0;
                const float s1 = xb[c + 1] + w1;
                const float s2 = xb[c + 2] + w2;
                const float s3 = xb[c + 3] + w3;
                amax[p] = fmax3(amax[p], fmax3(s0, s1, s2), s3);
                amin[p] = fmin3(amin[p], fmin3(s0, s1, s2), s3);
            }
        }
    }

    const float bv = bias[lane];
#pragma unroll
    for (int p = 0; p < PIX; ++p)
        out[(pix0 + p) * 64 + lane] = amax[p] - amin[p] + bv;
}

extern "C" void kernel_launch(void* const* d_in, const int* in_sizes, int n_in,
                              void* d_out, int out_size, void* d_ws, size_t ws_size,
                              hipStream_t stream) {
    const float* x    = (const float*)d_in[0];
    const float* w    = (const float*)d_in[1];
    const float* bias = (const float*)d_in[2];
    float* out = (float*)d_out;

    // 72 KiB dynamic LDS; 2 blocks/CU on 160 KiB.
    static int attr_done = 0;
    if (!attr_done) {
        (void)hipFuncSetAttribute((const void*)trop_kernel,
                                  hipFuncAttributeMaxDynamicSharedMemorySize,
                                  73728);
        attr_done = 1;
    }

    // 7200 pixels / (4 waves * 4 pixels) = 450 blocks
    trop_kernel<<<dim3(450), dim3(TPB), 73728, stream>>>(x, w, bias, out);
}